// Round 6
// baseline (259.079 us; speedup 1.0000x reference)
//
#include <hip/hip_runtime.h>
#include <hip/hip_bf16.h>

// Swin shifted-window attention, fused, bf16 MFMA (16x16x32).
// B=16 H=W=128 C=96 NH=3 d=32 WS=8 SS=4 -> L=64 tokens/window, 4096 blocks.
// R10: occupancy restructure (R7-R9 chain-cuts were all flat => TLP-starved):
//   - ownership flip: wave wv computes ALL 18 QKV n-tiles for its OWN 16 token
//     rows (af: 12 frags -> 3; same MFMA count; weights re-read from L2).
//     Rows m0..m0+15 are wave-private through the whole kernel.
//   - per-head K/V LDS: kb/vt hold ONE head; h-loop = {Q(2h,2h+1),K_h,V_h} ->
//     barrier -> attn(h) -> barrier.  LDS 39424 -> 22016 B => up to 7 blk/CU.
//   - x->Q reuse barrier dropped (rows wave-private); 6 barriers total.
// Carried: R9 K-row permutation (shuffle-free PV), kb chunk-XOR swizzle,
//   bias+mask folded into QK acc-init, pk2 conversions, exp2, bf16x2 bias table.
// Fragment layouts (verified on gfx950 via R4/R6):
//   A: lane holds A[m=lane&15][k=quad*8+j]
//   B: lane holds B[k=quad*8+j][n=lane&15]
//   C/D: lane holds (row=quad*4+reg, col=lane&15)

typedef __attribute__((ext_vector_type(8))) short short8;
typedef __attribute__((ext_vector_type(4))) float f32x4;

#define XST 104   // xs row stride (bf16): 208B, 2-way banks (free)
#define VST 72    // vt row stride: 144B

// ws layout:
//   shorts [0        .. 27647]  qkv_w bf16, row-major [col][96], cols 0..95 pre-scaled by qs/ln2
//   shorts [27648    .. 36863]  proj_w bf16, row-major [col][96]
//   bytes  73728..74879         qkv_b fp32 (288), cols 0..95 pre-scaled by qs/ln2
//   bytes  74880..75263         proj_b fp32 (96)
//   bytes  75776..100351        bias2 u32 [3][32][64]: bf16x2(rel_bias[h][q][2kp], [2kp+1]) / ln2
#define WS_QKVW 0
#define WS_PROJW 27648
#define WS_QKVB_BYTES 73728
#define WS_PROJB_BYTES 74880
#define WS_BIAST_BYTES 75776
#define WS_TOTAL_BYTES (WS_BIAST_BYTES + 3 * 32 * 64 * 4)

#define INV_LN2 1.4426950408889634f
#define MASK_NEG 144.26950408889634f   // 100/ln2

__device__ __forceinline__ unsigned short f2b(float f) {
    union { float f; unsigned u; } v; v.f = f;
    unsigned r = v.u + 0x7fffu + ((v.u >> 16) & 1u);   // RNE
    return (unsigned short)(r >> 16);
}

// packed f32x2 -> bf16x2 (RNE): lo = a, hi = b
__device__ __forceinline__ unsigned pk2(float a, float b) {
    union { __hip_bfloat162 h; unsigned u; } z;
    z.h = __float22bfloat162_rn(make_float2(a, b));
    return z.u;
}
__device__ __forceinline__ float blo(unsigned u) {
    union { unsigned u; float f; } z; z.u = u << 16; return z.f;
}
__device__ __forceinline__ float bhi(unsigned u) {
    union { unsigned u; float f; } z; z.u = u & 0xffff0000u; return z.f;
}

__global__ void prep_weights(const float* __restrict__ qkv_w,
                             const float* __restrict__ qkv_b,
                             const float* __restrict__ proj_w,
                             const float* __restrict__ proj_b,
                             const float* __restrict__ rel_bias,
                             void* __restrict__ ws, int do_bias)
{
    unsigned short* wsh = (unsigned short*)ws;
    float* fqb = (float*)((char*)ws + WS_QKVB_BYTES);
    float* fpb = (float*)((char*)ws + WS_PROJB_BYTES);
    unsigned* fb2 = (unsigned*)((char*)ws + WS_BIAST_BYTES);
    const float qs = 0.17677669529663687f * INV_LN2;  // 1/sqrt(32)/ln2

    int idx = blockIdx.x * 256 + threadIdx.x;
    if (idx < 27648) {                       // qkv_w
        int col = idx / 96;
        float v = qkv_w[idx];
        if (col < 96) v *= qs;
        wsh[WS_QKVW + idx] = f2b(v);
    } else if (idx < 36864) {                // proj_w
        wsh[WS_PROJW + (idx - 27648)] = f2b(proj_w[idx - 27648]);
    } else if (idx < 37152) {                // qkv_b
        int col = idx - 36864;
        float v = qkv_b[col];
        if (col < 96) v *= qs;
        fqb[col] = v;
    } else if (idx < 37248) {                // proj_b
        fpb[idx - 37152] = proj_b[idx - 37152];
    } else if (do_bias && idx < 43392) {     // bias2[h][kp][q]
        int i2 = idx - 37248;                // [0, 6144)
        int h = i2 >> 11;                    // 2048 per head
        int rem = i2 & 2047;
        int kp = rem >> 6, q = rem & 63;
        float lo = rel_bias[(h * 64 + q) * 64 + 2 * kp]     * INV_LN2;
        float hi = rel_bias[(h * 64 + q) * 64 + 2 * kp + 1] * INV_LN2;
        fb2[i2] = pk2(lo, hi);
    }
}

__global__ __launch_bounds__(256, 6) void swin_mfma(
    const float* __restrict__ x,
    const float* __restrict__ rel_bias,     // [h][q][k] fallback path
    const unsigned* __restrict__ bias2,     // [h][kp][q] bf16x2/ln2 in ws, or nullptr
    const void* __restrict__ ws,
    float* __restrict__ out)
{
    const unsigned short* wqkv  = (const unsigned short*)ws + WS_QKVW;
    const unsigned short* wproj = (const unsigned short*)ws + WS_PROJW;
    const float* wqkvb = (const float*)((const char*)ws + WS_QKVB_BYTES);
    const float* wprjb = (const float*)((const char*)ws + WS_PROJB_BYTES);

    __shared__ __align__(16) unsigned short xs[64 * XST];  // 13.0 KB: x -> Q -> attn-out
    __shared__ __align__(16) unsigned short kb[64 * 32];   //  4.0 KB: K (ONE head), permuted+swizzled
    __shared__ __align__(16) unsigned short vt[32 * VST];  //  4.5 KB: V^T (ONE head) [d][tok]
    // total 22016 B -> up to 7 blocks/CU

    const int t    = threadIdx.x;
    const int wv   = t >> 6;          // wave id 0..3 = token-row-strip owner
    const int lane = t & 63;
    const int quad = lane >> 4;
    const int l16  = lane & 15;
    const int m0   = wv * 16;

    const int blk = blockIdx.x;
    const int bb  = blk >> 8;
    const int win = blk & 255;
    const int wh  = win >> 4, ww = win & 15;

    // ---- stage x window -> bf16 LDS (rolled coords) ----
    for (int idx = t; idx < 1536; idx += 256) {
        int row = idx / 24;
        int c4  = idx - row * 24;
        int r = row >> 3, c = row & 7;
        int gh = (wh * 8 + r + 4) & 127;
        int gw = (ww * 8 + c + 4) & 127;
        float4 v = *(const float4*)&x[(((bb * 128 + gh) * 128 + gw) * 96) + c4 * 4];
        union { unsigned u[2]; ushort4 s; } pk;
        pk.u[0] = pk2(v.x, v.y);
        pk.u[1] = pk2(v.z, v.w);
        *(ushort4*)&xs[row * XST + c4 * 4] = pk.s;
    }
    __syncthreads();   // only cross-wave barrier on x; rows are wave-private after

    // ---- preload X A-frags for OWN rows only (12 VGPR) ----
    short8 af[3];
    #pragma unroll
    for (int ks = 0; ks < 3; ++ks)
        af[ks] = *(const short8*)&xs[(m0 + l16) * XST + ks * 32 + quad * 8];
    // No barrier: xs rows m0..m0+15 are read/written only by this wave from here.

    // generic 16-col QKV gemm for own rows: C[m0..m0+15][n0..n0+15]
    auto gemm16 = [&](int n0) -> f32x4 {
        float b = wqkvb[n0 + l16];
        f32x4 acc = (f32x4){b, b, b, b};
        #pragma unroll
        for (int ks = 0; ks < 3; ++ks) {
            short8 bf = *(const short8*)&wqkv[(n0 + l16) * 96 + ks * 32 + quad * 8];
            acc = __builtin_amdgcn_mfma_f32_16x16x32_bf16(af[ks], bf, acc, 0, 0, 0);
        }
        return acc;
    };

    // K-row permutation base: token t = m0 + quad*4 + r,
    // srow(t) = 32*t[5] + 16*t[2] + 4*t[4:3] + t[1:0]
    const int kbase = 32 * (wv >> 1) + 16 * (quad & 1) + 8 * (wv & 1) + 4 * (quad >> 1);

    const bool bh = (wh == 15), bw = (ww == 15);
    const bool edge = bh || bw;
    const int qtok = m0 + l16;
    const int qrr = bh ? (((qtok >> 3) < 4) ? 1 : 2) : 0;
    const int qcc = bw ? (((qtok & 7) < 4) ? 1 : 2) : 0;

    for (int h = 0; h < 3; ++h) {
        // ---- Q tiles 2h, 2h+1 -> xs (own rows) ----
        #pragma unroll
        for (int qi = 0; qi < 2; ++qi) {
            int qt = 2 * h + qi;
            f32x4 acc = gemm16(qt * 16);
            unsigned u01 = pk2(acc[0], acc[1]);
            unsigned u23 = pk2(acc[2], acc[3]);
            int rb = (m0 + quad * 4) * XST + qt * 16 + l16;
            xs[rb]           = (unsigned short)u01;
            xs[rb + XST]     = (unsigned short)(u01 >> 16);
            xs[rb + 2 * XST] = (unsigned short)u23;
            xs[rb + 3 * XST] = (unsigned short)(u23 >> 16);
        }
        // ---- K_h -> kb (permuted rows + chunk-XOR swizzle) ----
        #pragma unroll
        for (int half = 0; half < 2; ++half) {
            f32x4 acc = gemm16(96 + h * 32 + half * 16);
            int d = half * 16 + l16;
            int dch = d >> 3, dlo = d & 7;
            unsigned u01 = pk2(acc[0], acc[1]);
            unsigned u23 = pk2(acc[2], acc[3]);
            int c01 = ((dch ^ ((kbase >> 1) & 3)) << 3) + dlo;
            int c23 = ((dch ^ (((kbase >> 1) + 1) & 3)) << 3) + dlo;
            kb[(kbase + 0) * 32 + c01] = (unsigned short)u01;
            kb[(kbase + 1) * 32 + c01] = (unsigned short)(u01 >> 16);
            kb[(kbase + 2) * 32 + c23] = (unsigned short)u23;
            kb[(kbase + 3) * 32 + c23] = (unsigned short)(u23 >> 16);
        }
        // ---- V_h -> vt [d][tok] ----
        #pragma unroll
        for (int half = 0; half < 2; ++half) {
            f32x4 acc = gemm16(192 + h * 32 + half * 16);
            int d = half * 16 + l16;
            union { unsigned u[2]; ushort4 s; } pk;
            pk.u[0] = pk2(acc[0], acc[1]);
            pk.u[1] = pk2(acc[2], acc[3]);
            *(ushort4*)&vt[d * VST + m0 + quad * 4] = pk.s;
        }
        __syncthreads();   // kb/vt (and, via program order, Q) visible to all waves

        // ---- attention head h; s[nt][r] = S[q=m0+l16][k=32*(nt>>1)+8*quad+4*(nt&1)+r] ----
        {
            short8 qa = *(const short8*)&xs[(m0 + l16) * XST + h * 32 + quad * 8];
            f32x4 s[4];
            #pragma unroll
            for (int nt = 0; nt < 4; ++nt) {
                int k0 = 32 * (nt >> 1) + 8 * quad + 4 * (nt & 1);
                float bv[4];
                if (bias2) {
                    int kpb = k0 >> 1;
                    unsigned u0 = bias2[(h * 32 + kpb) * 64 + qtok];
                    unsigned u1 = bias2[(h * 32 + kpb + 1) * 64 + qtok];
                    bv[0] = blo(u0); bv[1] = bhi(u0);
                    bv[2] = blo(u1); bv[3] = bhi(u1);
                } else {
                    #pragma unroll
                    for (int r = 0; r < 4; ++r)
                        bv[r] = rel_bias[(h * 64 + qtok) * 64 + k0 + r] * INV_LN2;
                }
                f32x4 z;
                if (edge) {
                    #pragma unroll
                    for (int r = 0; r < 4; ++r) {
                        int ktok = k0 + r;
                        int krr = bh ? (((ktok >> 3) < 4) ? 1 : 2) : 0;
                        int kcc = bw ? (((ktok & 7) < 4) ? 1 : 2) : 0;
                        z[r] = bv[r] - ((krr != qrr || kcc != qcc) ? MASK_NEG : 0.f);
                    }
                } else {
                    z[0] = bv[0]; z[1] = bv[1]; z[2] = bv[2]; z[3] = bv[3];
                }
                int rowk = nt * 16 + l16;
                short8 kf = *(const short8*)&kb[rowk * 32 + ((quad ^ ((rowk >> 1) & 3)) << 3)];
                s[nt] = __builtin_amdgcn_mfma_f32_16x16x32_bf16(kf, qa, z, 0, 0, 0);
            }
            float p[4][4];
            float rs = 0.f;
            #pragma unroll
            for (int nt = 0; nt < 4; ++nt) {
                #pragma unroll
                for (int r = 0; r < 4; ++r) {
                    float e = exp2f(s[nt][r]);   // bias+mask already in s
                    p[nt][r] = e;
                    rs += e;
                }
            }
            rs += __shfl_xor(rs, 16);            // full row-sum across the 4 quads
            rs += __shfl_xor(rs, 32);
            float rinv = 1.0f / rs;

            // pa[kk][j] = P[q][k=kk*32+quad*8+j] -- lane-local (R9 permutation)
            short8 pa[2];
            #pragma unroll
            for (int kk = 0; kk < 2; ++kk) {
                union { unsigned u[4]; short8 s8; } uw;
                uw.u[0] = pk2(p[2 * kk][0] * rinv,     p[2 * kk][1] * rinv);
                uw.u[1] = pk2(p[2 * kk][2] * rinv,     p[2 * kk][3] * rinv);
                uw.u[2] = pk2(p[2 * kk + 1][0] * rinv, p[2 * kk + 1][1] * rinv);
                uw.u[3] = pk2(p[2 * kk + 1][2] * rinv, p[2 * kk + 1][3] * rinv);
                pa[kk] = uw.s8;
            }

            f32x4 o0 = (f32x4){0.f, 0.f, 0.f, 0.f};
            f32x4 o1 = o0;
            #pragma unroll
            for (int kk = 0; kk < 2; ++kk) {
                short8 v0 = *(const short8*)&vt[(l16) * VST + kk * 32 + quad * 8];
                short8 v1 = *(const short8*)&vt[(16 + l16) * VST + kk * 32 + quad * 8];
                o0 = __builtin_amdgcn_mfma_f32_16x16x32_bf16(pa[kk], v0, o0, 0, 0, 0);
                o1 = __builtin_amdgcn_mfma_f32_16x16x32_bf16(pa[kk], v1, o1, 0, 0, 0);
            }
            // attn-out -> xs cols h*32.. (own rows; P already normalized)
            int ob = (m0 + quad * 4) * XST + h * 32 + l16;
            unsigned a01 = pk2(o0[0], o0[1]);
            unsigned a23 = pk2(o0[2], o0[3]);
            unsigned b01 = pk2(o1[0], o1[1]);
            unsigned b23 = pk2(o1[2], o1[3]);
            xs[ob]                = (unsigned short)a01;
            xs[ob + XST]          = (unsigned short)(a01 >> 16);
            xs[ob + 2 * XST]      = (unsigned short)a23;
            xs[ob + 3 * XST]      = (unsigned short)(a23 >> 16);
            xs[ob + 16]           = (unsigned short)b01;
            xs[ob + XST + 16]     = (unsigned short)(b01 >> 16);
            xs[ob + 2 * XST + 16] = (unsigned short)b23;
            xs[ob + 3 * XST + 16] = (unsigned short)(b23 >> 16);
        }
        if (h < 2) __syncthreads();   // all waves done reading kb/vt before overwrite
    }
    // No barrier: proj reads only this wave's rows of xs (same-wave program order).

    // ---- proj GEMM: own rows x (6 n-tiles) x (3 k-steps) ----
    {
        short8 pja[3];
        #pragma unroll
        for (int ks = 0; ks < 3; ++ks)
            pja[ks] = *(const short8*)&xs[(m0 + l16) * XST + ks * 32 + quad * 8];

        int rowbase[4];
        #pragma unroll
        for (int r = 0; r < 4; ++r) {
            int tok = m0 + quad * 4 + r;
            int tr = tok >> 3, tc = tok & 7;
            int gh = (wh * 8 + tr + 4) & 127;
            int gw = (ww * 8 + tc + 4) & 127;
            rowbase[r] = ((bb * 128 + gh) * 128 + gw) * 96;
        }
        #pragma unroll
        for (int nt = 0; nt < 6; ++nt) {
            const int n0 = nt * 16;
            float bias = wprjb[n0 + l16];
            f32x4 acc = (f32x4){bias, bias, bias, bias};
            #pragma unroll
            for (int ks = 0; ks < 3; ++ks) {
                short8 bf = *(const short8*)&wproj[(n0 + l16) * 96 + ks * 32 + quad * 8];
                acc = __builtin_amdgcn_mfma_f32_16x16x32_bf16(pja[ks], bf, acc, 0, 0, 0);
            }
            #pragma unroll
            for (int r = 0; r < 4; ++r)
                out[rowbase[r] + n0 + l16] = acc[r];
        }
    }
}

extern "C" void kernel_launch(void* const* d_in, const int* in_sizes, int n_in,
                              void* d_out, int out_size, void* d_ws, size_t ws_size,
                              hipStream_t stream) {
    const float* x        = (const float*)d_in[0];
    const float* qkv_w    = (const float*)d_in[1];
    const float* qkv_b    = (const float*)d_in[2];
    const float* proj_w   = (const float*)d_in[3];
    const float* proj_b   = (const float*)d_in[4];
    const float* rel_bias = (const float*)d_in[5];
    float* out = (float*)d_out;

    const unsigned* bias2 = nullptr;
    if (ws_size >= (size_t)WS_TOTAL_BYTES)
        bias2 = (const unsigned*)((const char*)d_ws + WS_BIAST_BYTES);

    hipLaunchKernelGGL(prep_weights, dim3(170), dim3(256), 0, stream,
                       qkv_w, qkv_b, proj_w, proj_b, rel_bias, d_ws, bias2 ? 1 : 0);
    hipLaunchKernelGGL(swin_mfma, dim3(4096), dim3(256), 0, stream,
                       x, rel_bias, bias2, (const void*)d_ws, out);
}